// Round 7
// baseline (680.554 us; speedup 1.0000x reference)
//
#include <hip/hip_runtime.h>
#include <hip/hip_cooperative_groups.h>

namespace cg = cooperative_groups;

#define MAXDEG 192
#define NEG_SLOPE 0.2f
#define D 128

__device__ __forceinline__ float bf2f(unsigned short u) {
    return __uint_as_float(((unsigned)u) << 16);
}
__device__ __forceinline__ unsigned short f2bf(float f) {
    unsigned u = __float_as_uint(f);
    return (unsigned short)((u + 0x7fffu + ((u >> 16) & 1u)) >> 16);
}
__device__ __forceinline__ unsigned pack2bf(float x, float y) {
    return (unsigned)f2bf(x) | ((unsigned)f2bf(y) << 16);
}
// dtype detect: adj[0,0]==1.0 guaranteed (self-loop). f32 -> 0x3F800000.
__device__ __forceinline__ int is_f32(const void* adj) {
    return ((const unsigned*)adj)[0] == 0x3F800000u;
}

// --------------------------------------------------------------------------
// ELL compaction of one 4-row group (wave per row). Order-free.
// --------------------------------------------------------------------------
__device__ __forceinline__ void ell_group(
        int g, const void* __restrict__ adj, int N, int f32m,
        unsigned short* __restrict__ cols, int* __restrict__ deg,
        int* __restrict__ cnt /* 4 ints LDS */) {
    const int w = threadIdx.x >> 6, lane = threadIdx.x & 63;
    const int row = g * 4 + w;
    if (lane == 0) cnt[w] = 0;
    __syncthreads();
    unsigned short* crow = cols + (size_t)row * MAXDEG;
    if (f32m) {
        const float4* arow = (const float4*)((const float*)adj + (size_t)row * N);
        const int nv = N / 4;
        for (int v = lane; v < nv; v += 128) {
            float4 u0 = arow[v];
            float4 u1 = arow[v + 64];
            const unsigned* a0 = (const unsigned*)&u0;
            const unsigned* a1 = (const unsigned*)&u1;
            #pragma unroll
            for (int e = 0; e < 4; e++)
                if (a0[e]) { int p = atomicAdd(&cnt[w], 1); if (p < MAXDEG) crow[p] = (unsigned short)(v * 4 + e); }
            #pragma unroll
            for (int e = 0; e < 4; e++)
                if (a1[e]) { int p = atomicAdd(&cnt[w], 1); if (p < MAXDEG) crow[p] = (unsigned short)((v + 64) * 4 + e); }
        }
    } else {
        const uint4* arow = (const uint4*)((const unsigned short*)adj + (size_t)row * N);
        const int nv = N / 8;
        for (int v = lane; v < nv; v += 128) {
            uint4 u0 = arow[v];
            uint4 u1 = arow[v + 64];
            const unsigned short* s0 = (const unsigned short*)&u0;
            const unsigned short* s1 = (const unsigned short*)&u1;
            #pragma unroll
            for (int e = 0; e < 8; e++)
                if (s0[e]) { int p = atomicAdd(&cnt[w], 1); if (p < MAXDEG) crow[p] = (unsigned short)(v * 8 + e); }
            #pragma unroll
            for (int e = 0; e < 8; e++)
                if (s1[e]) { int p = atomicAdd(&cnt[w], 1); if (p < MAXDEG) crow[p] = (unsigned short)((v + 64) * 8 + e); }
        }
    }
    __syncthreads();
    if (lane == 0) deg[row] = cnt[w] < MAXDEG ? cnt[w] : MAXDEG;
}

// --------------------------------------------------------------------------
// 32x128 tile of H = A @ W (K=128), H written bf16, fused score epilogue.
// smem: xs=[0,4096) f32, ws=[4096,8192) f32 (32 KB).
// --------------------------------------------------------------------------
__device__ __forceinline__ void gemm_tile32(
        int t, const void* __restrict__ A, const void* __restrict__ W,
        int aF, int f32m, const void* __restrict__ attS, const void* __restrict__ attD,
        unsigned short* __restrict__ Hb, float* __restrict__ asrc, float* __restrict__ adst,
        float* __restrict__ smem) {
    float* xs = smem;
    float* ws = smem + 4096;
    const int tid = threadIdx.x;
    const size_t row0 = (size_t)t * 32;

    if (aF) {
        const float4* av = (const float4*)((const float*)A + row0 * D);
        float4* xl = (float4*)xs;
        #pragma unroll
        for (int k = 0; k < 4; k++) xl[tid + 256 * k] = av[tid + 256 * k];
    } else {
        const uint4* av = (const uint4*)((const unsigned short*)A + row0 * D);
        #pragma unroll
        for (int k = 0; k < 2; k++) {
            uint4 u = av[tid + 256 * k];
            const unsigned short* us = (const unsigned short*)&u;
            #pragma unroll
            for (int e = 0; e < 8; e++) xs[(tid + 256 * k) * 8 + e] = bf2f(us[e]);
        }
    }

    const int tx = tid & 31, ty = tid >> 5;
    const int c0 = tx * 4, r0 = ty * 4;
    float acc[4][4] = {};
    for (int p = 0; p < 4; p++) {
        __syncthreads();
        if (f32m) {
            const float4* wv = (const float4*)((const float*)W + (size_t)p * 32 * D);
            float4* wl = (float4*)ws;
            #pragma unroll
            for (int k = 0; k < 4; k++) wl[tid + 256 * k] = wv[tid + 256 * k];
        } else {
            const uint4* wv = (const uint4*)((const unsigned short*)W + (size_t)p * 32 * D);
            #pragma unroll
            for (int k = 0; k < 2; k++) {
                uint4 u = wv[tid + 256 * k];
                const unsigned short* us = (const unsigned short*)&u;
                #pragma unroll
                for (int e = 0; e < 8; e++) ws[(tid + 256 * k) * 8 + e] = bf2f(us[e]);
            }
        }
        __syncthreads();
        #pragma unroll 8
        for (int k = 0; k < 32; k++) {
            float4 wv = *(const float4*)&ws[k * D + c0];
            #pragma unroll
            for (int i = 0; i < 4; i++) {
                float xv = xs[(r0 + i) * D + p * 32 + k];
                acc[i][0] += xv * wv.x; acc[i][1] += xv * wv.y;
                acc[i][2] += xv * wv.z; acc[i][3] += xv * wv.w;
            }
        }
    }
    #pragma unroll
    for (int i = 0; i < 4; i++) {
        ushort4 hv;
        hv.x = f2bf(acc[i][0]); hv.y = f2bf(acc[i][1]);
        hv.z = f2bf(acc[i][2]); hv.w = f2bf(acc[i][3]);
        *(ushort4*)&Hb[(row0 + r0 + i) * D + c0] = hv;
    }

    float aSv[4], aDv[4];
    #pragma unroll
    for (int j = 0; j < 4; j++) {
        aSv[j] = f32m ? ((const float*)attS)[c0 + j] : bf2f(((const unsigned short*)attS)[c0 + j]);
        aDv[j] = f32m ? ((const float*)attD)[c0 + j] : bf2f(((const unsigned short*)attD)[c0 + j]);
    }
    #pragma unroll
    for (int i = 0; i < 4; i++) {
        float s = acc[i][0] * aSv[0] + acc[i][1] * aSv[1] + acc[i][2] * aSv[2] + acc[i][3] * aSv[3];
        float d = acc[i][0] * aDv[0] + acc[i][1] * aDv[1] + acc[i][2] * aDv[2] + acc[i][3] * aDv[3];
        #pragma unroll
        for (int off = 16; off > 0; off >>= 1) {
            s += __shfl_down(s, off, 32);
            d += __shfl_down(d, off, 32);
        }
        if (tx == 0) {
            asrc[row0 + r0 + i] = s;
            adst[row0 + r0 + i] = d;
        }
    }
}

// --------------------------------------------------------------------------
// Wave-local softmax + bf16 gather for one row.
// --------------------------------------------------------------------------
__device__ __forceinline__ float2 agg_row_bf(
        int row, const unsigned short* __restrict__ Hb,
        const float* __restrict__ asrc, float ai,
        const unsigned short* __restrict__ crow, int d,
        const void* __restrict__ bias, int f32m, int relu,
        float* __restrict__ scn, unsigned short* __restrict__ sjj, int lane) {
    const int s0 = lane, s1 = lane + 64, s2 = lane + 128;
    unsigned short j0 = 0, j1 = 0, j2 = 0;
    float e0 = -3e38f, e1 = -3e38f, e2 = -3e38f;
    if (s0 < d) { j0 = crow[s0]; float e = asrc[j0] + ai; e0 = (e >= 0.f) ? e : NEG_SLOPE * e; }
    if (s1 < d) { j1 = crow[s1]; float e = asrc[j1] + ai; e1 = (e >= 0.f) ? e : NEG_SLOPE * e; }
    if (s2 < d) { j2 = crow[s2]; float e = asrc[j2] + ai; e2 = (e >= 0.f) ? e : NEG_SLOPE * e; }
    float m = fmaxf(e0, fmaxf(e1, e2));
    #pragma unroll
    for (int off = 1; off < 64; off <<= 1) m = fmaxf(m, __shfl_xor(m, off));
    float p0 = (s0 < d) ? __expf(e0 - m) : 0.f;
    float p1 = (s1 < d) ? __expf(e1 - m) : 0.f;
    float p2 = (s2 < d) ? __expf(e2 - m) : 0.f;
    float l = p0 + p1 + p2;
    #pragma unroll
    for (int off = 1; off < 64; off <<= 1) l += __shfl_xor(l, off);
    const float invl = 1.f / l;
    scn[s0] = p0 * invl; sjj[s0] = j0;
    scn[s1] = p1 * invl; sjj[s1] = j1;
    scn[s2] = p2 * invl; sjj[s2] = j2;
    // same-wave LDS RAW: no block barrier needed

    const unsigned* H2 = (const unsigned*)Hb;  // 64 x (2 bf16) per row
    float ax[8], ay[8];
    #pragma unroll
    for (int u = 0; u < 8; u++) { ax[u] = 0.f; ay[u] = 0.f; }
    int k = 0;
    for (; k + 7 < d; k += 8) {
        int jj[8]; float ww[8]; unsigned vv[8];
        #pragma unroll
        for (int u = 0; u < 8; u++) { jj[u] = sjj[k + u]; ww[u] = scn[k + u]; }
        #pragma unroll
        for (int u = 0; u < 8; u++) vv[u] = H2[(size_t)jj[u] * 64 + lane];
        #pragma unroll
        for (int u = 0; u < 8; u++) {
            ax[u] += ww[u] * bf2f((unsigned short)(vv[u] & 0xffff));
            ay[u] += ww[u] * bf2f((unsigned short)(vv[u] >> 16));
        }
    }
    for (; k < d; k++) {
        const int j = sjj[k];
        const float wk = scn[k];
        unsigned v = H2[(size_t)j * 64 + lane];
        ax[0] += wk * bf2f((unsigned short)(v & 0xffff));
        ay[0] += wk * bf2f((unsigned short)(v >> 16));
    }
    #pragma unroll
    for (int u = 1; u < 8; u++) { ax[0] += ax[u]; ay[0] += ay[u]; }

    const int c0 = lane * 2;
    const float bx = f32m ? ((const float*)bias)[c0]     : bf2f(((const unsigned short*)bias)[c0]);
    const float by = f32m ? ((const float*)bias)[c0 + 1] : bf2f(((const unsigned short*)bias)[c0 + 1]);
    float vx = ax[0] + bx, vy = ay[0] + by;
    if (relu) { vx = fmaxf(vx, 0.f); vy = fmaxf(vy, 0.f); }
    return make_float2(vx, vy);
}

// --------------------------------------------------------------------------
// agg0 + gemm1 body for one 8-row group q (shared by coop + fallback).
// --------------------------------------------------------------------------
__device__ __forceinline__ void agg0_gemm1_body(
        int q, const unsigned short* __restrict__ h,
        const float* __restrict__ asrc0, const float* __restrict__ adst0,
        const unsigned short* __restrict__ cols, const int* __restrict__ deg,
        const void* __restrict__ b0, const void* __restrict__ W1,
        const void* __restrict__ aS1, const void* __restrict__ aD1, int f32m,
        void* __restrict__ out, unsigned short* __restrict__ h2,
        float* __restrict__ asrc1, float* __restrict__ adst1,
        float* __restrict__ xs8, float* __restrict__ wst,
        float* __restrict__ scnA, unsigned short* __restrict__ sjjA) {
    const int tid = threadIdx.x;
    const int w = tid >> 6, lane = tid & 63;

    // Phase A: aggregate 8 rows (2 passes x 4 waves), bf16/f32 out0 write
    #pragma unroll
    for (int pass = 0; pass < 2; pass++) {
        const int rl = pass * 4 + w;
        const int row = q * 8 + rl;
        float2 v = agg_row_bf(row, h, asrc0, adst0[row],
                              cols + (size_t)row * MAXDEG, deg[row],
                              b0, f32m, 1,
                              scnA + w * MAXDEG, sjjA + w * MAXDEG, lane);
        xs8[rl * D + 2 * lane]     = v.x;
        xs8[rl * D + 2 * lane + 1] = v.y;
        if (f32m) ((float2*)out)[(size_t)row * 64 + lane] = v;
        else      ((unsigned*)out)[(size_t)row * 64 + lane] = pack2bf(v.x, v.y);
    }

    // Phase B: gemm 8x128 @ 128x128 (W1 staged 32 rows at a time)
    const int tx = tid & 31, ty = tid >> 5;
    const int c0 = tx * 4;
    float acc[4] = {};
    for (int p = 0; p < 4; p++) {
        __syncthreads(); // xs8 writes visible (p=0) / prev wst reads done
        if (f32m) {
            const float4* wv = (const float4*)((const float*)W1 + (size_t)p * 32 * D);
            float4* wl = (float4*)wst;
            #pragma unroll
            for (int k = 0; k < 4; k++) wl[tid + 256 * k] = wv[tid + 256 * k];
        } else {
            const uint4* wv = (const uint4*)((const unsigned short*)W1 + (size_t)p * 32 * D);
            #pragma unroll
            for (int k = 0; k < 2; k++) {
                uint4 u = wv[tid + 256 * k];
                const unsigned short* us = (const unsigned short*)&u;
                #pragma unroll
                for (int e = 0; e < 8; e++) wst[(tid + 256 * k) * 8 + e] = bf2f(us[e]);
            }
        }
        __syncthreads();
        #pragma unroll 8
        for (int k = 0; k < 32; k++) {
            float4 wv = *(const float4*)&wst[k * D + c0];
            float xv = xs8[ty * D + p * 32 + k];
            acc[0] += xv * wv.x; acc[1] += xv * wv.y;
            acc[2] += xv * wv.z; acc[3] += xv * wv.w;
        }
    }
    const size_t row1 = (size_t)q * 8 + ty;
    ushort4 hv;
    hv.x = f2bf(acc[0]); hv.y = f2bf(acc[1]); hv.z = f2bf(acc[2]); hv.w = f2bf(acc[3]);
    *(ushort4*)&h2[row1 * D + c0] = hv;

    float aSv[4], aDv[4];
    #pragma unroll
    for (int j = 0; j < 4; j++) {
        aSv[j] = f32m ? ((const float*)aS1)[c0 + j] : bf2f(((const unsigned short*)aS1)[c0 + j]);
        aDv[j] = f32m ? ((const float*)aD1)[c0 + j] : bf2f(((const unsigned short*)aD1)[c0 + j]);
    }
    float s = acc[0] * aSv[0] + acc[1] * aSv[1] + acc[2] * aSv[2] + acc[3] * aSv[3];
    float d = acc[0] * aDv[0] + acc[1] * aDv[1] + acc[2] * aDv[2] + acc[3] * aDv[3];
    #pragma unroll
    for (int off = 16; off > 0; off >>= 1) {
        s += __shfl_down(s, off, 32);
        d += __shfl_down(d, off, 32);
    }
    if (tx == 0) {
        asrc1[row1] = s;
        adst1[row1] = d;
    }
}

// --------------------------------------------------------------------------
// Cooperative single-launch kernel: P0 (gemm0 + work-queued ELL) ->
// grid.sync -> P1 (agg0+gemm1) -> grid.sync -> P2 (agg1).
// --------------------------------------------------------------------------
__global__ __launch_bounds__(256) void gat_coop(
        const void* __restrict__ x, const void* __restrict__ adj,
        const void* __restrict__ W0, const void* __restrict__ aS0,
        const void* __restrict__ aD0, const void* __restrict__ b0,
        const void* __restrict__ W1, const void* __restrict__ aS1,
        const void* __restrict__ aD1, const void* __restrict__ b1,
        void* __restrict__ out, int N,
        int* __restrict__ qhead, int* __restrict__ deg,
        unsigned short* __restrict__ cols,
        unsigned short* __restrict__ h, unsigned short* __restrict__ h2,
        float* __restrict__ asrc0, float* __restrict__ adst0,
        float* __restrict__ asrc1, float* __restrict__ adst1) {
    cg::grid_group grid = cg::this_grid();
    __shared__ __align__(16) char smemRaw[32768];
    __shared__ int sgrp;
    float* smemF = (float*)smemRaw;
    float* xs8   = (float*)smemRaw;                     // 4 KB
    float* wst   = (float*)(smemRaw + 4096);            // 16 KB
    float* scnA  = (float*)(smemRaw + 20480);           // 3 KB
    unsigned short* sjjA = (unsigned short*)(smemRaw + 23552); // 1.5 KB
    const int G = gridDim.x;
    const int f32m = is_f32(adj);
    const int GT = N / 32, NG = N / 4;

    // ---- P0: gemm layer0 (grid-stride over tiles) + work-queued ELL
    for (int t = blockIdx.x; t < GT; t += G) {
        __syncthreads();
        gemm_tile32(t, x, W0, f32m, f32m, aS0, aD0, h, asrc0, adst0, smemF);
    }
    __syncthreads();
    for (;;) {
        if (threadIdx.x == 0) sgrp = atomicAdd(qhead, 1);
        __syncthreads();
        const int g = sgrp;
        if (g >= NG) break;
        ell_group(g, adj, N, f32m, cols, deg, (int*)smemRaw);
    }
    __threadfence();
    grid.sync();

    // ---- P1: agg layer0 + gemm layer1 (8 rows per block-iter)
    for (int q = blockIdx.x; q < N / 8; q += G) {
        __syncthreads(); // prev-iter phase-B reads done before xs8 rewrite
        agg0_gemm1_body(q, h, asrc0, adst0, cols, deg, b0, W1, aS1, aD1, f32m,
                        out, h2, asrc1, adst1, xs8, wst, scnA, sjjA);
    }
    __threadfence();
    grid.sync();

    // ---- P2: agg layer1 (4 rows per block-iter; wave-private LDS only)
    const int w = threadIdx.x >> 6, lane = threadIdx.x & 63;
    for (int q = blockIdx.x; q < N / 4; q += G) {
        const int row = q * 4 + w;
        float2 v = agg_row_bf(row, h2, asrc1, adst1[row],
                              cols + (size_t)row * MAXDEG, deg[row],
                              b1, f32m, 0,
                              scnA + w * MAXDEG, sjjA + w * MAXDEG, lane);
        const size_t off2 = (size_t)N * 64;
        if (f32m) ((float2*)out)[off2 + (size_t)row * 64 + lane] = v;
        else      ((unsigned*)out)[off2 + (size_t)row * 64 + lane] = pack2bf(v.x, v.y);
    }
}

// --------------------------------------------------------------------------
// Fallback 3-kernel path (proven round-6 structure).
// --------------------------------------------------------------------------
__global__ __launch_bounds__(256) void ell_gemm0(
        const void* __restrict__ x, const void* __restrict__ adj,
        const void* __restrict__ W0, const void* __restrict__ aS0,
        const void* __restrict__ aD0, int N,
        unsigned short* __restrict__ cols, int* __restrict__ deg,
        unsigned short* __restrict__ h, float* __restrict__ asrc, float* __restrict__ adst) {
    __shared__ float smem[8192]; // 32 KB
    const int bid = blockIdx.x;
    const int f32m = is_f32(adj);
    const int GT = N / 32;
    if (bid < GT)
        gemm_tile32(bid, x, W0, f32m, f32m, aS0, aD0, h, asrc, adst, smem);
    else
        ell_group(bid - GT, adj, N, f32m, cols, deg, (int*)smem);
}

__global__ __launch_bounds__(256) void agg0_gemm1(
        const unsigned short* __restrict__ h,
        const float* __restrict__ asrc0, const float* __restrict__ adst0,
        const unsigned short* __restrict__ cols, const int* __restrict__ deg,
        const void* __restrict__ b0, const void* __restrict__ W1,
        const void* __restrict__ aS1, const void* __restrict__ aD1,
        const void* __restrict__ adjFlag, void* __restrict__ out,
        unsigned short* __restrict__ h2,
        float* __restrict__ asrc1, float* __restrict__ adst1, int N) {
    __shared__ float xs8[8 * D];
    __shared__ float wst[32 * D];
    __shared__ float scnA[4 * MAXDEG];
    __shared__ unsigned short sjjA[4 * MAXDEG];
    const int f32m = is_f32(adjFlag);
    agg0_gemm1_body(blockIdx.x, h, asrc0, adst0, cols, deg, b0, W1, aS1, aD1,
                    f32m, out, h2, asrc1, adst1, xs8, wst, scnA, sjjA);
}

__global__ __launch_bounds__(256) void aggregate1(
        const unsigned short* __restrict__ h2,
        const float* __restrict__ asrc1, const float* __restrict__ adst1,
        const unsigned short* __restrict__ cols, const int* __restrict__ deg,
        const void* __restrict__ b1, const void* __restrict__ adjFlag,
        void* __restrict__ out, int N) {
    __shared__ float scnA[4 * MAXDEG];
    __shared__ unsigned short sjjA[4 * MAXDEG];
    const int w = threadIdx.x >> 6, lane = threadIdx.x & 63;
    const int row = blockIdx.x * 4 + w;
    const int f32m = is_f32(adjFlag);
    float2 v = agg_row_bf(row, h2, asrc1, adst1[row],
                          cols + (size_t)row * MAXDEG, deg[row],
                          b1, f32m, 0,
                          scnA + w * MAXDEG, sjjA + w * MAXDEG, lane);
    const size_t off2 = (size_t)N * 64;
    if (f32m) ((float2*)out)[off2 + (size_t)row * 64 + lane] = v;
    else      ((unsigned*)out)[off2 + (size_t)row * 64 + lane] = pack2bf(v.x, v.y);
}

// --------------------------------------------------------------------------
extern "C" void kernel_launch(void* const* d_in, const int* in_sizes, int n_in,
                              void* d_out, int out_size, void* d_ws, size_t ws_size,
                              hipStream_t stream) {
    const int N = in_sizes[0] / D; // 8192

    char* w = (char*)d_ws;
    int* qhead           = (int*)w;            w += 256;
    int* deg             = (int*)w;            w += (size_t)N * sizeof(int);
    unsigned short* cols = (unsigned short*)w; w += (size_t)N * MAXDEG * sizeof(unsigned short);
    unsigned short* h    = (unsigned short*)w; w += (size_t)N * D * sizeof(unsigned short);
    unsigned short* h2   = (unsigned short*)w; w += (size_t)N * D * sizeof(unsigned short);
    float* asrc0         = (float*)w;          w += (size_t)N * sizeof(float);
    float* adst0         = (float*)w;          w += (size_t)N * sizeof(float);
    float* asrc1         = (float*)w;          w += (size_t)N * sizeof(float);
    float* adst1         = (float*)w;

    const void* adj = d_in[1];

    hipMemsetAsync(qhead, 0, 64, stream); // zero ELL work-queue head

    // Grid size from occupancy (host-side query; capture-safe). Cap at 1024.
    int bpc = 0;
    hipError_t qe = hipOccupancyMaxActiveBlocksPerMultiprocessor(&bpc, gat_coop, 256, 0);
    int G = (qe == hipSuccess && bpc > 0) ? bpc * 256 : 512;
    if (G > 1024) G = 1024;

    const void* a_x = d_in[0];
    const void* a_W0 = d_in[2]; const void* a_aS0 = d_in[3];
    const void* a_aD0 = d_in[4]; const void* a_b0 = d_in[5];
    const void* a_W1 = d_in[6]; const void* a_aS1 = d_in[7];
    const void* a_aD1 = d_in[8]; const void* a_b1 = d_in[9];
    void* a_out = d_out; int a_N = N;
    void* args[] = {
        (void*)&a_x, (void*)&adj, (void*)&a_W0, (void*)&a_aS0, (void*)&a_aD0,
        (void*)&a_b0, (void*)&a_W1, (void*)&a_aS1, (void*)&a_aD1, (void*)&a_b1,
        (void*)&a_out, (void*)&a_N, (void*)&qhead, (void*)&deg, (void*)&cols,
        (void*)&h, (void*)&h2, (void*)&asrc0, (void*)&adst0,
        (void*)&asrc1, (void*)&adst1
    };

    hipError_t ce = hipLaunchCooperativeKernel(
        reinterpret_cast<void*>(gat_coop), dim3(G), dim3(256), args, 0, stream);

    if (ce != hipSuccess) {
        // Deterministic fallback: proven 3-kernel path (identical math).
        ell_gemm0<<<N / 32 + N / 4, 256, 0, stream>>>(
            d_in[0], adj, d_in[2], d_in[3], d_in[4], N, cols, deg, h, asrc0, adst0);
        agg0_gemm1<<<N / 8, 256, 0, stream>>>(
            h, asrc0, adst0, cols, deg, d_in[5], d_in[6], d_in[7], d_in[8],
            adj, d_out, h2, asrc1, adst1, N);
        aggregate1<<<N / 4, 256, 0, stream>>>(
            h2, asrc1, adst1, cols, deg, d_in[9], adj, d_out, N);
    }
}

// Round 8
// 428.169 us; speedup vs baseline: 1.5895x; 1.5895x over previous
//
#include <hip/hip_runtime.h>

#define MAXDEG 192
#define NEG_SLOPE 0.2f
#define D 128

__device__ __forceinline__ float bf2f(unsigned short u) {
    return __uint_as_float(((unsigned)u) << 16);
}
__device__ __forceinline__ unsigned short f2bf(float f) {
    unsigned u = __float_as_uint(f);
    return (unsigned short)((u + 0x7fffu + ((u >> 16) & 1u)) >> 16);
}
__device__ __forceinline__ unsigned pack2bf(float x, float y) {
    return (unsigned)f2bf(x) | ((unsigned)f2bf(y) << 16);
}
// dtype detect: adj[0,0]==1.0 guaranteed (self-loop). f32 -> 0x3F800000.
__device__ __forceinline__ int is_f32(const void* adj) {
    return ((const unsigned*)adj)[0] == 0x3F800000u;
}

// --------------------------------------------------------------------------
// ELL compaction of one 4-row group (wave per row). Order-free.
// 4 uint4 loads in flight per lane; 32-bit-word nonzero tests.
// --------------------------------------------------------------------------
__device__ __forceinline__ void ell_scan_u4_bf16(
        uint4 u, int base, int* cnt, unsigned short* crow) {
    const unsigned* a = (const unsigned*)&u;
    #pragma unroll
    for (int e = 0; e < 4; e++) {
        unsigned wv = a[e];
        if (wv) {
            if (wv & 0xffffu) {
                int p = atomicAdd(cnt, 1);
                if (p < MAXDEG) crow[p] = (unsigned short)(base + 2 * e);
            }
            if (wv >> 16) {
                int p = atomicAdd(cnt, 1);
                if (p < MAXDEG) crow[p] = (unsigned short)(base + 2 * e + 1);
            }
        }
    }
}

__device__ __forceinline__ void ell_group(
        int g, const void* __restrict__ adj, int N, int f32m,
        unsigned short* __restrict__ cols, int* __restrict__ deg,
        int* __restrict__ cnt /* 4 ints LDS */) {
    const int w = threadIdx.x >> 6, lane = threadIdx.x & 63;
    const int row = g * 4 + w;
    if (lane == 0) cnt[w] = 0;
    __syncthreads();
    unsigned short* crow = cols + (size_t)row * MAXDEG;
    if (f32m) {
        const float4* arow = (const float4*)((const float*)adj + (size_t)row * N);
        const int nv = N / 4; // 2048, multiple of 256
        for (int v = lane; v < nv; v += 256) {
            float4 u0 = arow[v];
            float4 u1 = arow[v + 64];
            float4 u2 = arow[v + 128];
            float4 u3 = arow[v + 192];
            const float4* us[4] = {&u0, &u1, &u2, &u3};
            #pragma unroll
            for (int q = 0; q < 4; q++) {
                const unsigned* a = (const unsigned*)us[q];
                const int base = (v + 64 * q) * 4;
                #pragma unroll
                for (int e = 0; e < 4; e++)
                    if (a[e]) { int p = atomicAdd(&cnt[w], 1); if (p < MAXDEG) crow[p] = (unsigned short)(base + e); }
            }
        }
    } else {
        const uint4* arow = (const uint4*)((const unsigned short*)adj + (size_t)row * N);
        const int nv = N / 8; // 1024, multiple of 256
        for (int v = lane; v < nv; v += 256) {
            uint4 u0 = arow[v];
            uint4 u1 = arow[v + 64];
            uint4 u2 = arow[v + 128];
            uint4 u3 = arow[v + 192];
            ell_scan_u4_bf16(u0, (v)       * 8, &cnt[w], crow);
            ell_scan_u4_bf16(u1, (v + 64)  * 8, &cnt[w], crow);
            ell_scan_u4_bf16(u2, (v + 128) * 8, &cnt[w], crow);
            ell_scan_u4_bf16(u3, (v + 192) * 8, &cnt[w], crow);
        }
    }
    __syncthreads();
    if (lane == 0) deg[row] = cnt[w] < MAXDEG ? cnt[w] : MAXDEG;
}

// --------------------------------------------------------------------------
// 32x128 tile of H = A @ W (K=128), H written bf16, fused score epilogue.
// W staged 16 rows/phase: smem = xs 16 KB + wst 8 KB = 24 KB (6 blocks/CU).
// --------------------------------------------------------------------------
__device__ __forceinline__ void gemm_tile32(
        int t, const void* __restrict__ A, const void* __restrict__ W,
        int aF, int f32m, const void* __restrict__ attS, const void* __restrict__ attD,
        unsigned short* __restrict__ Hb, float* __restrict__ asrc, float* __restrict__ adst,
        float* __restrict__ smem) {
    float* xs = smem;          // 32*128 f32 = 16 KB
    float* ws = smem + 4096;   // 16*128 f32 =  8 KB
    const int tid = threadIdx.x;
    const size_t row0 = (size_t)t * 32;

    if (aF) {
        const float4* av = (const float4*)((const float*)A + row0 * D);
        float4* xl = (float4*)xs;
        #pragma unroll
        for (int k = 0; k < 4; k++) xl[tid + 256 * k] = av[tid + 256 * k];
    } else {
        const uint4* av = (const uint4*)((const unsigned short*)A + row0 * D);
        #pragma unroll
        for (int k = 0; k < 2; k++) {
            uint4 u = av[tid + 256 * k];
            const unsigned short* us = (const unsigned short*)&u;
            #pragma unroll
            for (int e = 0; e < 8; e++) xs[(tid + 256 * k) * 8 + e] = bf2f(us[e]);
        }
    }

    const int tx = tid & 31, ty = tid >> 5;
    const int c0 = tx * 4, r0 = ty * 4;
    float acc[4][4] = {};
    for (int p = 0; p < 8; p++) {
        __syncthreads();
        if (f32m) {       // 16x128 f32 = 512 float4
            const float4* wv = (const float4*)((const float*)W + (size_t)p * 16 * D);
            float4* wl = (float4*)ws;
            #pragma unroll
            for (int k = 0; k < 2; k++) wl[tid + 256 * k] = wv[tid + 256 * k];
        } else {          // 16x128 bf16 = 256 uint4
            uint4 u = ((const uint4*)((const unsigned short*)W + (size_t)p * 16 * D))[tid];
            const unsigned short* us = (const unsigned short*)&u;
            #pragma unroll
            for (int e = 0; e < 8; e++) ws[tid * 8 + e] = bf2f(us[e]);
        }
        __syncthreads();
        #pragma unroll 8
        for (int k = 0; k < 16; k++) {
            float4 wv = *(const float4*)&ws[k * D + c0];
            #pragma unroll
            for (int i = 0; i < 4; i++) {
                float xv = xs[(r0 + i) * D + p * 16 + k];
                acc[i][0] += xv * wv.x; acc[i][1] += xv * wv.y;
                acc[i][2] += xv * wv.z; acc[i][3] += xv * wv.w;
            }
        }
    }
    #pragma unroll
    for (int i = 0; i < 4; i++) {
        ushort4 hv;
        hv.x = f2bf(acc[i][0]); hv.y = f2bf(acc[i][1]);
        hv.z = f2bf(acc[i][2]); hv.w = f2bf(acc[i][3]);
        *(ushort4*)&Hb[(row0 + r0 + i) * D + c0] = hv;
    }

    float aSv[4], aDv[4];
    #pragma unroll
    for (int j = 0; j < 4; j++) {
        aSv[j] = f32m ? ((const float*)attS)[c0 + j] : bf2f(((const unsigned short*)attS)[c0 + j]);
        aDv[j] = f32m ? ((const float*)attD)[c0 + j] : bf2f(((const unsigned short*)attD)[c0 + j]);
    }
    #pragma unroll
    for (int i = 0; i < 4; i++) {
        float s = acc[i][0] * aSv[0] + acc[i][1] * aSv[1] + acc[i][2] * aSv[2] + acc[i][3] * aSv[3];
        float d = acc[i][0] * aDv[0] + acc[i][1] * aDv[1] + acc[i][2] * aDv[2] + acc[i][3] * aDv[3];
        #pragma unroll
        for (int off = 16; off > 0; off >>= 1) {
            s += __shfl_down(s, off, 32);
            d += __shfl_down(d, off, 32);
        }
        if (tx == 0) {
            asrc[row0 + r0 + i] = s;
            adst[row0 + r0 + i] = d;
        }
    }
}

// --------------------------------------------------------------------------
// Wave-local softmax + bf16 gather for one row (8 independent chains).
// --------------------------------------------------------------------------
__device__ __forceinline__ float2 agg_row_bf(
        int row, const unsigned short* __restrict__ Hb,
        const float* __restrict__ asrc, float ai,
        const unsigned short* __restrict__ crow, int d,
        const void* __restrict__ bias, int f32m, int relu,
        float* __restrict__ scn, unsigned short* __restrict__ sjj, int lane) {
    const int s0 = lane, s1 = lane + 64, s2 = lane + 128;
    unsigned short j0 = 0, j1 = 0, j2 = 0;
    float e0 = -3e38f, e1 = -3e38f, e2 = -3e38f;
    if (s0 < d) { j0 = crow[s0]; float e = asrc[j0] + ai; e0 = (e >= 0.f) ? e : NEG_SLOPE * e; }
    if (s1 < d) { j1 = crow[s1]; float e = asrc[j1] + ai; e1 = (e >= 0.f) ? e : NEG_SLOPE * e; }
    if (s2 < d) { j2 = crow[s2]; float e = asrc[j2] + ai; e2 = (e >= 0.f) ? e : NEG_SLOPE * e; }
    float m = fmaxf(e0, fmaxf(e1, e2));
    #pragma unroll
    for (int off = 1; off < 64; off <<= 1) m = fmaxf(m, __shfl_xor(m, off));
    float p0 = (s0 < d) ? __expf(e0 - m) : 0.f;
    float p1 = (s1 < d) ? __expf(e1 - m) : 0.f;
    float p2 = (s2 < d) ? __expf(e2 - m) : 0.f;
    float l = p0 + p1 + p2;
    #pragma unroll
    for (int off = 1; off < 64; off <<= 1) l += __shfl_xor(l, off);
    const float invl = 1.f / l;
    scn[s0] = p0 * invl; sjj[s0] = j0;
    scn[s1] = p1 * invl; sjj[s1] = j1;
    scn[s2] = p2 * invl; sjj[s2] = j2;
    // same-wave LDS RAW: no block barrier needed

    const unsigned* H2 = (const unsigned*)Hb;  // 64 x (2 bf16) per row
    float ax[8], ay[8];
    #pragma unroll
    for (int u = 0; u < 8; u++) { ax[u] = 0.f; ay[u] = 0.f; }
    int k = 0;
    for (; k + 7 < d; k += 8) {
        int jj[8]; float ww[8]; unsigned vv[8];
        #pragma unroll
        for (int u = 0; u < 8; u++) { jj[u] = sjj[k + u]; ww[u] = scn[k + u]; }
        #pragma unroll
        for (int u = 0; u < 8; u++) vv[u] = H2[(size_t)jj[u] * 64 + lane];
        #pragma unroll
        for (int u = 0; u < 8; u++) {
            ax[u] += ww[u] * bf2f((unsigned short)(vv[u] & 0xffff));
            ay[u] += ww[u] * bf2f((unsigned short)(vv[u] >> 16));
        }
    }
    for (; k < d; k++) {
        const int j = sjj[k];
        const float wk = scn[k];
        unsigned v = H2[(size_t)j * 64 + lane];
        ax[0] += wk * bf2f((unsigned short)(v & 0xffff));
        ay[0] += wk * bf2f((unsigned short)(v >> 16));
    }
    #pragma unroll
    for (int u = 1; u < 8; u++) { ax[0] += ax[u]; ay[0] += ay[u]; }

    const int c0 = lane * 2;
    const float bx = f32m ? ((const float*)bias)[c0]     : bf2f(((const unsigned short*)bias)[c0]);
    const float by = f32m ? ((const float*)bias)[c0 + 1] : bf2f(((const unsigned short*)bias)[c0 + 1]);
    float vx = ax[0] + bx, vy = ay[0] + by;
    if (relu) { vx = fmaxf(vx, 0.f); vy = fmaxf(vy, 0.f); }
    return make_float2(vx, vy);
}

// --------------------------------------------------------------------------
// K1: blocks [0, N/4) do ELL compaction (dispatched FIRST -- the HBM-bound
// long pole starts at full residency); blocks [N/4, N/4+N/32) do gemm0.
// --------------------------------------------------------------------------
__global__ __launch_bounds__(256) void ell_gemm0(
        const void* __restrict__ x, const void* __restrict__ adj,
        const void* __restrict__ W0, const void* __restrict__ aS0,
        const void* __restrict__ aD0, int N,
        unsigned short* __restrict__ cols, int* __restrict__ deg,
        unsigned short* __restrict__ h, float* __restrict__ asrc, float* __restrict__ adst) {
    __shared__ float smem[6144]; // 24 KB -> 6 blocks/CU
    const int bid = blockIdx.x;
    const int f32m = is_f32(adj);
    const int NG = N / 4;
    if (bid < NG)
        ell_group(bid, adj, N, f32m, cols, deg, (int*)smem);
    else
        gemm_tile32(bid - NG, x, W0, f32m, f32m, aS0, aD0, h, asrc, adst, smem);
}

// --------------------------------------------------------------------------
// K2: fused aggregate-layer0 + gemm-layer1 for 8 rows per block.
// --------------------------------------------------------------------------
__global__ __launch_bounds__(256) void agg0_gemm1(
        const unsigned short* __restrict__ h,
        const float* __restrict__ asrc0, const float* __restrict__ adst0,
        const unsigned short* __restrict__ cols, const int* __restrict__ deg,
        const void* __restrict__ b0, const void* __restrict__ W1,
        const void* __restrict__ aS1, const void* __restrict__ aD1,
        const void* __restrict__ adjFlag, void* __restrict__ out,
        unsigned short* __restrict__ h2,
        float* __restrict__ asrc1, float* __restrict__ adst1, int N) {
    __shared__ float xs8[8 * D];        // 4 KB
    __shared__ float wst[32 * D];       // 16 KB
    __shared__ float scnA[4 * MAXDEG];
    __shared__ unsigned short sjjA[4 * MAXDEG];
    const int tid = threadIdx.x;
    const int w = tid >> 6, lane = tid & 63;
    const int f32m = is_f32(adjFlag);
    const int q = blockIdx.x;

    // Phase A: aggregate 8 rows (2 passes x 4 waves) + out0 write
    #pragma unroll
    for (int pass = 0; pass < 2; pass++) {
        const int rl = pass * 4 + w;
        const int row = q * 8 + rl;
        float2 v = agg_row_bf(row, h, asrc0, adst0[row],
                              cols + (size_t)row * MAXDEG, deg[row],
                              b0, f32m, 1,
                              scnA + w * MAXDEG, sjjA + w * MAXDEG, lane);
        xs8[rl * D + 2 * lane]     = v.x;
        xs8[rl * D + 2 * lane + 1] = v.y;
        if (f32m) ((float2*)out)[(size_t)row * 64 + lane] = v;
        else      ((unsigned*)out)[(size_t)row * 64 + lane] = pack2bf(v.x, v.y);
    }

    // Phase B: gemm 8x128 @ 128x128 (W1 staged 32 rows/phase)
    const int tx = tid & 31, ty = tid >> 5;
    const int c0 = tx * 4;
    float acc[4] = {};
    for (int p = 0; p < 4; p++) {
        __syncthreads(); // xs8 visible (p=0) / prev wst reads done
        if (f32m) {
            const float4* wv = (const float4*)((const float*)W1 + (size_t)p * 32 * D);
            float4* wl = (float4*)wst;
            #pragma unroll
            for (int k = 0; k < 4; k++) wl[tid + 256 * k] = wv[tid + 256 * k];
        } else {
            const uint4* wv = (const uint4*)((const unsigned short*)W1 + (size_t)p * 32 * D);
            #pragma unroll
            for (int k = 0; k < 2; k++) {
                uint4 u = wv[tid + 256 * k];
                const unsigned short* us = (const unsigned short*)&u;
                #pragma unroll
                for (int e = 0; e < 8; e++) wst[(tid + 256 * k) * 8 + e] = bf2f(us[e]);
            }
        }
        __syncthreads();
        #pragma unroll 8
        for (int k = 0; k < 32; k++) {
            float4 wv = *(const float4*)&wst[k * D + c0];
            float xv = xs8[ty * D + p * 32 + k];
            acc[0] += xv * wv.x; acc[1] += xv * wv.y;
            acc[2] += xv * wv.z; acc[3] += xv * wv.w;
        }
    }
    const size_t row1 = (size_t)q * 8 + ty;
    ushort4 hv;
    hv.x = f2bf(acc[0]); hv.y = f2bf(acc[1]); hv.z = f2bf(acc[2]); hv.w = f2bf(acc[3]);
    *(ushort4*)&h2[row1 * D + c0] = hv;

    float aSv[4], aDv[4];
    #pragma unroll
    for (int j = 0; j < 4; j++) {
        aSv[j] = f32m ? ((const float*)aS1)[c0 + j] : bf2f(((const unsigned short*)aS1)[c0 + j]);
        aDv[j] = f32m ? ((const float*)aD1)[c0 + j] : bf2f(((const unsigned short*)aD1)[c0 + j]);
    }
    float s = acc[0] * aSv[0] + acc[1] * aSv[1] + acc[2] * aSv[2] + acc[3] * aSv[3];
    float d = acc[0] * aDv[0] + acc[1] * aDv[1] + acc[2] * aDv[2] + acc[3] * aDv[3];
    #pragma unroll
    for (int off = 16; off > 0; off >>= 1) {
        s += __shfl_down(s, off, 32);
        d += __shfl_down(d, off, 32);
    }
    if (tx == 0) {
        asrc1[row1] = s;
        adst1[row1] = d;
    }
}

// --------------------------------------------------------------------------
// K3: aggregate layer1 (4 rows/block), final output.
// --------------------------------------------------------------------------
__global__ __launch_bounds__(256) void aggregate1(
        const unsigned short* __restrict__ h2,
        const float* __restrict__ asrc1, const float* __restrict__ adst1,
        const unsigned short* __restrict__ cols, const int* __restrict__ deg,
        const void* __restrict__ b1, const void* __restrict__ adjFlag,
        void* __restrict__ out, int N) {
    __shared__ float scnA[4 * MAXDEG];
    __shared__ unsigned short sjjA[4 * MAXDEG];
    const int w = threadIdx.x >> 6, lane = threadIdx.x & 63;
    const int row = blockIdx.x * 4 + w;
    const int f32m = is_f32(adjFlag);
    float2 v = agg_row_bf(row, h2, asrc1, adst1[row],
                          cols + (size_t)row * MAXDEG, deg[row],
                          b1, f32m, 0,
                          scnA + w * MAXDEG, sjjA + w * MAXDEG, lane);
    const size_t off2 = (size_t)N * 64;
    if (f32m) ((float2*)out)[off2 + (size_t)row * 64 + lane] = v;
    else      ((unsigned*)out)[off2 + (size_t)row * 64 + lane] = pack2bf(v.x, v.y);
}

// --------------------------------------------------------------------------
extern "C" void kernel_launch(void* const* d_in, const int* in_sizes, int n_in,
                              void* d_out, int out_size, void* d_ws, size_t ws_size,
                              hipStream_t stream) {
    const int N = in_sizes[0] / D; // 8192

    char* w = (char*)d_ws;
    int* deg             = (int*)w;            w += (size_t)N * sizeof(int);
    unsigned short* cols = (unsigned short*)w; w += (size_t)N * MAXDEG * sizeof(unsigned short);
    unsigned short* h    = (unsigned short*)w; w += (size_t)N * D * sizeof(unsigned short);
    unsigned short* h2   = (unsigned short*)w; w += (size_t)N * D * sizeof(unsigned short);
    float* asrc0         = (float*)w;          w += (size_t)N * sizeof(float);
    float* adst0         = (float*)w;          w += (size_t)N * sizeof(float);
    float* asrc1         = (float*)w;          w += (size_t)N * sizeof(float);
    float* adst1         = (float*)w;

    const void* adj = d_in[1];

    // K1: ELL build (first, HBM long pole) + gemm layer0
    ell_gemm0<<<N / 4 + N / 32, 256, 0, stream>>>(
        d_in[0], adj, d_in[2], d_in[3], d_in[4], N, cols, deg, h, asrc0, adst0);

    // K2: aggregate layer0 + gemm layer1
    agg0_gemm1<<<N / 8, 256, 0, stream>>>(
        h, asrc0, adst0, cols, deg, d_in[5], d_in[6], d_in[7], d_in[8],
        adj, d_out, h2, asrc1, adst1, N);

    // K3: aggregate layer1 (final output)
    aggregate1<<<N / 4, 256, 0, stream>>>(
        h2, asrc1, adst1, cols, deg, d_in[9], adj, d_out, N);
}

// Round 9
// 425.481 us; speedup vs baseline: 1.5995x; 1.0063x over previous
//
#include <hip/hip_runtime.h>

#define MAXDEG 192
#define NEG_SLOPE 0.2f
#define D 128

__device__ __forceinline__ float bf2f(unsigned short u) {
    return __uint_as_float(((unsigned)u) << 16);
}
__device__ __forceinline__ unsigned short f2bf(float f) {
    unsigned u = __float_as_uint(f);
    return (unsigned short)((u + 0x7fffu + ((u >> 16) & 1u)) >> 16);
}
__device__ __forceinline__ unsigned pack2bf(float x, float y) {
    return (unsigned)f2bf(x) | ((unsigned)f2bf(y) << 16);
}
// dtype detect: adj[0,0]==1.0 guaranteed (self-loop). f32 -> 0x3F800000.
__device__ __forceinline__ int is_f32(const void* adj) {
    return ((const unsigned*)adj)[0] == 0x3F800000u;
}

// --------------------------------------------------------------------------
// ELL compaction of one 4-row group (wave per row). Order-free.
// (R6-measured variant: stride-128, 2 loads in flight per lane.)
// --------------------------------------------------------------------------
__device__ __forceinline__ void ell_group(
        int g, const void* __restrict__ adj, int N, int f32m,
        unsigned short* __restrict__ cols, int* __restrict__ deg,
        int* __restrict__ cnt /* 4 ints LDS */) {
    const int w = threadIdx.x >> 6, lane = threadIdx.x & 63;
    const int row = g * 4 + w;
    if (lane == 0) cnt[w] = 0;
    __syncthreads();
    unsigned short* crow = cols + (size_t)row * MAXDEG;
    if (f32m) {
        const float4* arow = (const float4*)((const float*)adj + (size_t)row * N);
        const int nv = N / 4;
        for (int v = lane; v < nv; v += 128) {
            float4 u0 = arow[v];
            float4 u1 = arow[v + 64];
            const unsigned* a0 = (const unsigned*)&u0;
            const unsigned* a1 = (const unsigned*)&u1;
            #pragma unroll
            for (int e = 0; e < 4; e++)
                if (a0[e]) { int p = atomicAdd(&cnt[w], 1); if (p < MAXDEG) crow[p] = (unsigned short)(v * 4 + e); }
            #pragma unroll
            for (int e = 0; e < 4; e++)
                if (a1[e]) { int p = atomicAdd(&cnt[w], 1); if (p < MAXDEG) crow[p] = (unsigned short)((v + 64) * 4 + e); }
        }
    } else {
        const uint4* arow = (const uint4*)((const unsigned short*)adj + (size_t)row * N);
        const int nv = N / 8;
        for (int v = lane; v < nv; v += 128) {
            uint4 u0 = arow[v];
            uint4 u1 = arow[v + 64];
            const unsigned short* s0 = (const unsigned short*)&u0;
            const unsigned short* s1 = (const unsigned short*)&u1;
            #pragma unroll
            for (int e = 0; e < 8; e++)
                if (s0[e]) { int p = atomicAdd(&cnt[w], 1); if (p < MAXDEG) crow[p] = (unsigned short)(v * 8 + e); }
            #pragma unroll
            for (int e = 0; e < 8; e++)
                if (s1[e]) { int p = atomicAdd(&cnt[w], 1); if (p < MAXDEG) crow[p] = (unsigned short)((v + 64) * 8 + e); }
        }
    }
    __syncthreads();
    if (lane == 0) deg[row] = cnt[w] < MAXDEG ? cnt[w] : MAXDEG;
}

// --------------------------------------------------------------------------
// 32x128 tile of H = A @ W (K=128), H written bf16, fused score epilogue.
// W staged 32 rows/phase: smem = xs 16 KB + ws 16 KB = 32 KB (R6-measured).
// --------------------------------------------------------------------------
__device__ __forceinline__ void gemm_tile32(
        int t, const void* __restrict__ A, const void* __restrict__ W,
        int aF, int f32m, const void* __restrict__ attS, const void* __restrict__ attD,
        unsigned short* __restrict__ Hb, float* __restrict__ asrc, float* __restrict__ adst,
        float* __restrict__ smem) {
    float* xs = smem;
    float* ws = smem + 4096;
    const int tid = threadIdx.x;
    const size_t row0 = (size_t)t * 32;

    if (aF) {
        const float4* av = (const float4*)((const float*)A + row0 * D);
        float4* xl = (float4*)xs;
        #pragma unroll
        for (int k = 0; k < 4; k++) xl[tid + 256 * k] = av[tid + 256 * k];
    } else {
        const uint4* av = (const uint4*)((const unsigned short*)A + row0 * D);
        #pragma unroll
        for (int k = 0; k < 2; k++) {
            uint4 u = av[tid + 256 * k];
            const unsigned short* us = (const unsigned short*)&u;
            #pragma unroll
            for (int e = 0; e < 8; e++) xs[(tid + 256 * k) * 8 + e] = bf2f(us[e]);
        }
    }

    const int tx = tid & 31, ty = tid >> 5;
    const int c0 = tx * 4, r0 = ty * 4;
    float acc[4][4] = {};
    for (int p = 0; p < 4; p++) {
        __syncthreads();
        if (f32m) {
            const float4* wv = (const float4*)((const float*)W + (size_t)p * 32 * D);
            float4* wl = (float4*)ws;
            #pragma unroll
            for (int k = 0; k < 4; k++) wl[tid + 256 * k] = wv[tid + 256 * k];
        } else {
            const uint4* wv = (const uint4*)((const unsigned short*)W + (size_t)p * 32 * D);
            #pragma unroll
            for (int k = 0; k < 2; k++) {
                uint4 u = wv[tid + 256 * k];
                const unsigned short* us = (const unsigned short*)&u;
                #pragma unroll
                for (int e = 0; e < 8; e++) ws[(tid + 256 * k) * 8 + e] = bf2f(us[e]);
            }
        }
        __syncthreads();
        #pragma unroll 8
        for (int k = 0; k < 32; k++) {
            float4 wv = *(const float4*)&ws[k * D + c0];
            #pragma unroll
            for (int i = 0; i < 4; i++) {
                float xv = xs[(r0 + i) * D + p * 32 + k];
                acc[i][0] += xv * wv.x; acc[i][1] += xv * wv.y;
                acc[i][2] += xv * wv.z; acc[i][3] += xv * wv.w;
            }
        }
    }
    #pragma unroll
    for (int i = 0; i < 4; i++) {
        ushort4 hv;
        hv.x = f2bf(acc[i][0]); hv.y = f2bf(acc[i][1]);
        hv.z = f2bf(acc[i][2]); hv.w = f2bf(acc[i][3]);
        *(ushort4*)&Hb[(row0 + r0 + i) * D + c0] = hv;
    }

    float aSv[4], aDv[4];
    #pragma unroll
    for (int j = 0; j < 4; j++) {
        aSv[j] = f32m ? ((const float*)attS)[c0 + j] : bf2f(((const unsigned short*)attS)[c0 + j]);
        aDv[j] = f32m ? ((const float*)attD)[c0 + j] : bf2f(((const unsigned short*)attD)[c0 + j]);
    }
    #pragma unroll
    for (int i = 0; i < 4; i++) {
        float s = acc[i][0] * aSv[0] + acc[i][1] * aSv[1] + acc[i][2] * aSv[2] + acc[i][3] * aSv[3];
        float d = acc[i][0] * aDv[0] + acc[i][1] * aDv[1] + acc[i][2] * aDv[2] + acc[i][3] * aDv[3];
        #pragma unroll
        for (int off = 16; off > 0; off >>= 1) {
            s += __shfl_down(s, off, 32);
            d += __shfl_down(d, off, 32);
        }
        if (tx == 0) {
            asrc[row0 + r0 + i] = s;
            adst[row0 + r0 + i] = d;
        }
    }
}

// --------------------------------------------------------------------------
// Wave-local softmax + bf16 gather for one row (8 independent chains).
// --------------------------------------------------------------------------
__device__ __forceinline__ float2 agg_row_bf(
        int row, const unsigned short* __restrict__ Hb,
        const float* __restrict__ asrc, float ai,
        const unsigned short* __restrict__ crow, int d,
        const void* __restrict__ bias, int f32m, int relu,
        float* __restrict__ scn, unsigned short* __restrict__ sjj, int lane) {
    const int s0 = lane, s1 = lane + 64, s2 = lane + 128;
    unsigned short j0 = 0, j1 = 0, j2 = 0;
    float e0 = -3e38f, e1 = -3e38f, e2 = -3e38f;
    if (s0 < d) { j0 = crow[s0]; float e = asrc[j0] + ai; e0 = (e >= 0.f) ? e : NEG_SLOPE * e; }
    if (s1 < d) { j1 = crow[s1]; float e = asrc[j1] + ai; e1 = (e >= 0.f) ? e : NEG_SLOPE * e; }
    if (s2 < d) { j2 = crow[s2]; float e = asrc[j2] + ai; e2 = (e >= 0.f) ? e : NEG_SLOPE * e; }
    float m = fmaxf(e0, fmaxf(e1, e2));
    #pragma unroll
    for (int off = 1; off < 64; off <<= 1) m = fmaxf(m, __shfl_xor(m, off));
    float p0 = (s0 < d) ? __expf(e0 - m) : 0.f;
    float p1 = (s1 < d) ? __expf(e1 - m) : 0.f;
    float p2 = (s2 < d) ? __expf(e2 - m) : 0.f;
    float l = p0 + p1 + p2;
    #pragma unroll
    for (int off = 1; off < 64; off <<= 1) l += __shfl_xor(l, off);
    const float invl = 1.f / l;
    scn[s0] = p0 * invl; sjj[s0] = j0;
    scn[s1] = p1 * invl; sjj[s1] = j1;
    scn[s2] = p2 * invl; sjj[s2] = j2;
    // same-wave LDS RAW: no block barrier needed

    const unsigned* H2 = (const unsigned*)Hb;  // 64 x (2 bf16) per row
    float ax[8], ay[8];
    #pragma unroll
    for (int u = 0; u < 8; u++) { ax[u] = 0.f; ay[u] = 0.f; }
    int k = 0;
    for (; k + 7 < d; k += 8) {
        int jj[8]; float ww[8]; unsigned vv[8];
        #pragma unroll
        for (int u = 0; u < 8; u++) { jj[u] = sjj[k + u]; ww[u] = scn[k + u]; }
        #pragma unroll
        for (int u = 0; u < 8; u++) vv[u] = H2[(size_t)jj[u] * 64 + lane];
        #pragma unroll
        for (int u = 0; u < 8; u++) {
            ax[u] += ww[u] * bf2f((unsigned short)(vv[u] & 0xffff));
            ay[u] += ww[u] * bf2f((unsigned short)(vv[u] >> 16));
        }
    }
    for (; k < d; k++) {
        const int j = sjj[k];
        const float wk = scn[k];
        unsigned v = H2[(size_t)j * 64 + lane];
        ax[0] += wk * bf2f((unsigned short)(v & 0xffff));
        ay[0] += wk * bf2f((unsigned short)(v >> 16));
    }
    #pragma unroll
    for (int u = 1; u < 8; u++) { ax[0] += ax[u]; ay[0] += ay[u]; }

    const int c0 = lane * 2;
    const float bx = f32m ? ((const float*)bias)[c0]     : bf2f(((const unsigned short*)bias)[c0]);
    const float by = f32m ? ((const float*)bias)[c0 + 1] : bf2f(((const unsigned short*)bias)[c0 + 1]);
    float vx = ax[0] + bx, vy = ay[0] + by;
    if (relu) { vx = fmaxf(vx, 0.f); vy = fmaxf(vy, 0.f); }
    return make_float2(vx, vy);
}

// --------------------------------------------------------------------------
// K1: blocks [0, N/4) do ELL compaction (dispatched first: HBM long pole
// starts at full residency); blocks [N/4, N/4+N/32) do gemm layer0.
// --------------------------------------------------------------------------
__global__ __launch_bounds__(256) void ell_gemm0(
        const void* __restrict__ x, const void* __restrict__ adj,
        const void* __restrict__ W0, const void* __restrict__ aS0,
        const void* __restrict__ aD0, int N,
        unsigned short* __restrict__ cols, int* __restrict__ deg,
        unsigned short* __restrict__ h, float* __restrict__ asrc, float* __restrict__ adst) {
    __shared__ float smem[8192]; // 32 KB (R6-measured best)
    const int bid = blockIdx.x;
    const int f32m = is_f32(adj);
    const int NG = N / 4;
    if (bid < NG)
        ell_group(bid, adj, N, f32m, cols, deg, (int*)smem);
    else
        gemm_tile32(bid - NG, x, W0, f32m, f32m, aS0, aD0, h, asrc, adst, smem);
}

// --------------------------------------------------------------------------
// K2: fused aggregate-layer0 + gemm-layer1 for 8 rows per block.
// --------------------------------------------------------------------------
__global__ __launch_bounds__(256) void agg0_gemm1(
        const unsigned short* __restrict__ h,
        const float* __restrict__ asrc0, const float* __restrict__ adst0,
        const unsigned short* __restrict__ cols, const int* __restrict__ deg,
        const void* __restrict__ b0, const void* __restrict__ W1,
        const void* __restrict__ aS1, const void* __restrict__ aD1,
        const void* __restrict__ adjFlag, void* __restrict__ out,
        unsigned short* __restrict__ h2,
        float* __restrict__ asrc1, float* __restrict__ adst1, int N) {
    __shared__ float xs8[8 * D];        // 4 KB
    __shared__ float wst[32 * D];       // 16 KB
    __shared__ float scnA[4 * MAXDEG];
    __shared__ unsigned short sjjA[4 * MAXDEG];
    const int tid = threadIdx.x;
    const int w = tid >> 6, lane = tid & 63;
    const int f32m = is_f32(adjFlag);
    const int q = blockIdx.x;

    // Phase A: aggregate 8 rows (2 passes x 4 waves) + out0 write
    #pragma unroll
    for (int pass = 0; pass < 2; pass++) {
        const int rl = pass * 4 + w;
        const int row = q * 8 + rl;
        float2 v = agg_row_bf(row, h, asrc0, adst0[row],
                              cols + (size_t)row * MAXDEG, deg[row],
                              b0, f32m, 1,
                              scnA + w * MAXDEG, sjjA + w * MAXDEG, lane);
        xs8[rl * D + 2 * lane]     = v.x;
        xs8[rl * D + 2 * lane + 1] = v.y;
        if (f32m) ((float2*)out)[(size_t)row * 64 + lane] = v;
        else      ((unsigned*)out)[(size_t)row * 64 + lane] = pack2bf(v.x, v.y);
    }

    // Phase B: gemm 8x128 @ 128x128 (W1 staged 32 rows/phase)
    const int tx = tid & 31, ty = tid >> 5;
    const int c0 = tx * 4;
    float acc[4] = {};
    for (int p = 0; p < 4; p++) {
        __syncthreads(); // xs8 visible (p=0) / prev wst reads done
        if (f32m) {
            const float4* wv = (const float4*)((const float*)W1 + (size_t)p * 32 * D);
            float4* wl = (float4*)wst;
            #pragma unroll
            for (int k = 0; k < 4; k++) wl[tid + 256 * k] = wv[tid + 256 * k];
        } else {
            const uint4* wv = (const uint4*)((const unsigned short*)W1 + (size_t)p * 32 * D);
            #pragma unroll
            for (int k = 0; k < 2; k++) {
                uint4 u = wv[tid + 256 * k];
                const unsigned short* us = (const unsigned short*)&u;
                #pragma unroll
                for (int e = 0; e < 8; e++) wst[(tid + 256 * k) * 8 + e] = bf2f(us[e]);
            }
        }
        __syncthreads();
        #pragma unroll 8
        for (int k = 0; k < 32; k++) {
            float4 wv = *(const float4*)&wst[k * D + c0];
            float xv = xs8[ty * D + p * 32 + k];
            acc[0] += xv * wv.x; acc[1] += xv * wv.y;
            acc[2] += xv * wv.z; acc[3] += xv * wv.w;
        }
    }
    const size_t row1 = (size_t)q * 8 + ty;
    ushort4 hv;
    hv.x = f2bf(acc[0]); hv.y = f2bf(acc[1]); hv.z = f2bf(acc[2]); hv.w = f2bf(acc[3]);
    *(ushort4*)&h2[row1 * D + c0] = hv;

    float aSv[4], aDv[4];
    #pragma unroll
    for (int j = 0; j < 4; j++) {
        aSv[j] = f32m ? ((const float*)aS1)[c0 + j] : bf2f(((const unsigned short*)aS1)[c0 + j]);
        aDv[j] = f32m ? ((const float*)aD1)[c0 + j] : bf2f(((const unsigned short*)aD1)[c0 + j]);
    }
    float s = acc[0] * aSv[0] + acc[1] * aSv[1] + acc[2] * aSv[2] + acc[3] * aSv[3];
    float d = acc[0] * aDv[0] + acc[1] * aDv[1] + acc[2] * aDv[2] + acc[3] * aDv[3];
    #pragma unroll
    for (int off = 16; off > 0; off >>= 1) {
        s += __shfl_down(s, off, 32);
        d += __shfl_down(d, off, 32);
    }
    if (tx == 0) {
        asrc1[row1] = s;
        adst1[row1] = d;
    }
}

// --------------------------------------------------------------------------
// K3: aggregate layer1 (4 rows/block), final output.
// --------------------------------------------------------------------------
__global__ __launch_bounds__(256) void aggregate1(
        const unsigned short* __restrict__ h2,
        const float* __restrict__ asrc1, const float* __restrict__ adst1,
        const unsigned short* __restrict__ cols, const int* __restrict__ deg,
        const void* __restrict__ b1, const void* __restrict__ adjFlag,
        void* __restrict__ out, int N) {
    __shared__ float scnA[4 * MAXDEG];
    __shared__ unsigned short sjjA[4 * MAXDEG];
    const int w = threadIdx.x >> 6, lane = threadIdx.x & 63;
    const int row = blockIdx.x * 4 + w;
    const int f32m = is_f32(adjFlag);
    float2 v = agg_row_bf(row, h2, asrc1, adst1[row],
                          cols + (size_t)row * MAXDEG, deg[row],
                          b1, f32m, 0,
                          scnA + w * MAXDEG, sjjA + w * MAXDEG, lane);
    const size_t off2 = (size_t)N * 64;
    if (f32m) ((float2*)out)[off2 + (size_t)row * 64 + lane] = v;
    else      ((unsigned*)out)[off2 + (size_t)row * 64 + lane] = pack2bf(v.x, v.y);
}

// --------------------------------------------------------------------------
extern "C" void kernel_launch(void* const* d_in, const int* in_sizes, int n_in,
                              void* d_out, int out_size, void* d_ws, size_t ws_size,
                              hipStream_t stream) {
    const int N = in_sizes[0] / D; // 8192

    char* w = (char*)d_ws;
    int* deg             = (int*)w;            w += (size_t)N * sizeof(int);
    unsigned short* cols = (unsigned short*)w; w += (size_t)N * MAXDEG * sizeof(unsigned short);
    unsigned short* h    = (unsigned short*)w; w += (size_t)N * D * sizeof(unsigned short);
    unsigned short* h2   = (unsigned short*)w; w += (size_t)N * D * sizeof(unsigned short);
    float* asrc0         = (float*)w;          w += (size_t)N * sizeof(float);
    float* adst0         = (float*)w;          w += (size_t)N * sizeof(float);
    float* asrc1         = (float*)w;          w += (size_t)N * sizeof(float);
    float* adst1         = (float*)w;

    const void* adj = d_in[1];

    // K1: ELL build (first, HBM long pole) + gemm layer0
    ell_gemm0<<<N / 4 + N / 32, 256, 0, stream>>>(
        d_in[0], adj, d_in[2], d_in[3], d_in[4], N, cols, deg, h, asrc0, adst0);

    // K2: aggregate layer0 + gemm layer1
    agg0_gemm1<<<N / 8, 256, 0, stream>>>(
        h, asrc0, adst0, cols, deg, d_in[5], d_in[6], d_in[7], d_in[8],
        adj, d_out, h2, asrc1, adst1, N);

    // K3: aggregate layer1 (final output)
    aggregate1<<<N / 4, 256, 0, stream>>>(
        h2, asrc1, adst1, cols, deg, d_in[9], adj, d_out, N);
}